// Round 3
// baseline (229.066 us; speedup 1.0000x reference)
//
#include <hip/hip_runtime.h>

typedef _Float16 f16;
typedef _Float16 f16x8 __attribute__((ext_vector_type(8)));
typedef _Float16 f16x4 __attribute__((ext_vector_type(4)));
typedef _Float16 f16x2 __attribute__((ext_vector_type(2)));
typedef float f32x4 __attribute__((ext_vector_type(4)));
typedef float f32x2 __attribute__((ext_vector_type(2)));

#define MFMA16(a, b, c) __builtin_amdgcn_mfma_f32_16x16x32_f16(a, b, c, 0, 0, 0)

#define HID 4096
#define ROWS 128      // B*S
#define SCL 0.12751743f  // (1/sqrt(128)) * log2(e)

__device__ __forceinline__ f16x8 cvt8(float4 x, float4 y) {
    f16x8 v = {(f16)x.x, (f16)x.y, (f16)x.z, (f16)x.w,
               (f16)y.x, (f16)y.y, (f16)y.z, (f16)y.w};
    return v;
}

// XOR swizzle for a tile with 128 f16 (256 B) row pitch
__device__ __forceinline__ int swz2(int row, int cb) {
    return row * 256 + (cb ^ ((row & 7) << 4));
}

// ---------------- kernel 0: h fp32 -> f16 ----------------
__global__ void k_cvt(const float* __restrict__ src, f16* __restrict__ dst) {
    const int i = blockIdx.x * blockDim.x + threadIdx.x;
    const float4* s4 = (const float4*)src + (size_t)i * 2;
    float4 x = s4[0], y = s4[1];
    *((f16x8*)dst + i) = cvt8(x, y);
}

// ---------------- kernel Q: Q projection (single matrix, N=16) ----------------
__global__ __launch_bounds__(256) void k_qproj(
        const f16* __restrict__ hb, const float* __restrict__ W,
        f16* __restrict__ Ob) {
    const int c0 = blockIdx.x * 16;

    __shared__ __align__(16) f16 sA[128 * 128];
    __shared__ __align__(16) f16 sB[16 * 128];

    const int tid = threadIdx.x;
    const int w = tid >> 6, l = tid & 63;
    const int rw = w * 32;
    const int ar = tid >> 4;
    const int ac = (tid & 15) * 8;

    f32x4 acc0 = {}, acc1 = {};

    float4 wx, wy;
    f16x8 hreg[8];
    {
        const float* wp = W + (size_t)(c0 + ar) * HID + ac;
        wx = *(const float4*)wp; wy = *(const float4*)(wp + 4);
        #pragma unroll
        for (int c = 0; c < 8; ++c)
            hreg[c] = *(const f16x8*)(hb + (size_t)(c * 16 + ar) * HID + ac);
    }

    for (int ks = 0; ks < 32; ++ks) {
        #pragma unroll
        for (int c = 0; c < 8; ++c)
            *(f16x8*)((char*)sA + swz2(c * 16 + ar, ac * 2)) = hreg[c];
        *(f16x8*)((char*)sB + swz2(ar, ac * 2)) = cvt8(wx, wy);
        __syncthreads();
        if (ks < 31) {
            const int k0 = (ks + 1) * 128;
            const float* wp = W + (size_t)(c0 + ar) * HID + k0 + ac;
            wx = *(const float4*)wp; wy = *(const float4*)(wp + 4);
            #pragma unroll
            for (int c = 0; c < 8; ++c)
                hreg[c] = *(const f16x8*)(hb + (size_t)(c * 16 + ar) * HID + k0 + ac);
        }
        #pragma unroll
        for (int kk = 0; kk < 4; ++kk) {
            const int cb = kk * 64 + (l >> 4) * 16;
            f16x8 a0 = *(const f16x8*)((char*)sA + swz2(rw + (l & 15), cb));
            f16x8 a1 = *(const f16x8*)((char*)sA + swz2(rw + 16 + (l & 15), cb));
            f16x8 b0 = *(const f16x8*)((char*)sB + swz2((l & 15), cb));
            acc0 = MFMA16(a0, b0, acc0);
            acc1 = MFMA16(a1, b0, acc1);
        }
        __syncthreads();
    }
    #pragma unroll
    for (int r = 0; r < 4; ++r) {
        const int col = c0 + (l & 15);
        Ob[(size_t)(rw + (l >> 4) * 4 + r) * HID + col]      = (f16)acc0[r];
        Ob[(size_t)(rw + 16 + (l >> 4) * 4 + r) * HID + col] = (f16)acc1[r];
    }
}

// ---------------- kernel M: heterogeneous mega ----------------
// even blockIdx: attention over pure (fully-cached) tiles -> partial (m,l,O)
// odd  blockIdx: K/V projection (N=32 per block)
__global__ __launch_bounds__(512) void k_mega(
        const f16* __restrict__ hb,
        const float* __restrict__ Wk, const float* __restrict__ Wv,
        f16* __restrict__ Kw, f16* __restrict__ Vw,
        const f16* __restrict__ Qw,
        const float* __restrict__ Kc, const float* __restrict__ Vc,
        const int* __restrict__ posp,
        float* __restrict__ Pm, float* __restrict__ Pl, float* __restrict__ Po) {

    __shared__ __align__(16) char smem[65536 + 1024];
    const int tid = threadIdx.x, w = tid >> 6, l = tid & 63;

    if (blockIdx.x & 1) {
        // ================= K/V projection block =================
        const int pid = blockIdx.x >> 1;            // 0..255
        const float* __restrict__ W = (pid & 128) ? Wv : Wk;
        f16* __restrict__ Ob = (pid & 128) ? Vw : Kw;
        const int c0 = (pid & 127) * 32;

        f16* sA = (f16*)smem;                 // 128 x 128
        f16* sB = (f16*)smem + 128 * 128;     // 32 x 128

        const int ar = tid >> 4;              // 0..31
        const int ac = (tid & 15) * 8;

        f32x4 acc0 = {}, acc1 = {};

        float4 wx, wy;
        f16x8 hreg[4];
        {
            const float* wp = W + (size_t)(c0 + ar) * HID + ac;
            wx = *(const float4*)wp; wy = *(const float4*)(wp + 4);
            #pragma unroll
            for (int c = 0; c < 4; ++c)
                hreg[c] = *(const f16x8*)(hb + (size_t)(c * 32 + ar) * HID + ac);
        }

        const int rw = (w >> 1) * 32;
        const int cw = (w & 1) * 16;

        for (int ks = 0; ks < 32; ++ks) {
            #pragma unroll
            for (int c = 0; c < 4; ++c)
                *(f16x8*)((char*)sA + swz2(c * 32 + ar, ac * 2)) = hreg[c];
            *(f16x8*)((char*)sB + swz2(ar, ac * 2)) = cvt8(wx, wy);
            __syncthreads();
            if (ks < 31) {
                const int k0 = (ks + 1) * 128;
                const float* wp = W + (size_t)(c0 + ar) * HID + k0 + ac;
                wx = *(const float4*)wp; wy = *(const float4*)(wp + 4);
                #pragma unroll
                for (int c = 0; c < 4; ++c)
                    hreg[c] = *(const f16x8*)(hb + (size_t)(c * 32 + ar) * HID + k0 + ac);
            }
            #pragma unroll
            for (int kk = 0; kk < 4; ++kk) {
                const int cb = kk * 64 + (l >> 4) * 16;
                f16x8 a0 = *(const f16x8*)((char*)sA + swz2(rw + (l & 15), cb));
                f16x8 a1 = *(const f16x8*)((char*)sA + swz2(rw + 16 + (l & 15), cb));
                f16x8 b0 = *(const f16x8*)((char*)sB + swz2(cw + (l & 15), cb));
                acc0 = MFMA16(a0, b0, acc0);
                acc1 = MFMA16(a1, b0, acc1);
            }
            __syncthreads();
        }
        #pragma unroll
        for (int r = 0; r < 4; ++r) {
            const int col = c0 + cw + (l & 15);
            Ob[(size_t)(rw + (l >> 4) * 4 + r) * HID + col]      = (f16)acc0[r];
            Ob[(size_t)(rw + 16 + (l >> 4) * 4 + r) * HID + col] = (f16)acc1[r];
        }
        return;
    }

    // ================= attention pure-tile block =================
    const int bh = blockIdx.x >> 1;
    const int b = bh >> 5, hh = bh & 31;
    const int pos = *posp;
    const int npure = pos >> 5;

    const float* Kb = Kc + (size_t)bh * (4096 * 128);
    const float* Vb = Vc + (size_t)bh * (4096 * 128);

    f16x8 qf[4];
    {
        const f16* qp = Qw + (size_t)(b * 16 + (l & 15)) * HID + hh * 128 + (l >> 4) * 8;
        #pragma unroll
        for (int kk = 0; kk < 4; ++kk) qf[kk] = *(const f16x8*)(qp + kk * 32);
    }

    f32x4 o[8] = {};
    float m[4], lsum[4];
    #pragma unroll
    for (int r = 0; r < 4; ++r) { m[r] = -3e38f; lsum[r] = 0.f; }

    f16* Pw = (f16*)smem + w * 640;

    const int start = (w * npure) >> 3;
    const int end   = ((w + 1) * npure) >> 3;
    for (int tau = start; tau < end; ++tau) {
        const int t0 = tau << 5;

        f16x8 kf[2][4];
        #pragma unroll
        for (int tn = 0; tn < 2; ++tn) {
            const float* kp = Kb + (size_t)(t0 + tn * 16 + (l & 15)) * 128 + (l >> 4) * 8;
            #pragma unroll
            for (int kk = 0; kk < 4; ++kk) {
                float4 x = *(const float4*)(kp + kk * 32);
                float4 y = *(const float4*)(kp + kk * 32 + 4);
                kf[tn][kk] = cvt8(x, y);
            }
        }
        f32x4 sa[2] = {};
        #pragma unroll
        for (int tn = 0; tn < 2; ++tn)
            #pragma unroll
            for (int kk = 0; kk < 4; ++kk) sa[tn] = MFMA16(qf[kk], kf[tn][kk], sa[tn]);

        // V gather issued now; latency hides under softmax + P transpose
        f16x8 vf[8];
        {
            const float* vp = Vb + (size_t)(t0 + (l >> 4) * 8) * 128 + (l & 15);
            #pragma unroll
            for (int dt = 0; dt < 8; ++dt)
                #pragma unroll
                for (int j = 0; j < 8; ++j) vf[dt][j] = (f16)vp[j * 128 + dt * 16];
        }

        float sc[2][4];
        #pragma unroll
        for (int tn = 0; tn < 2; ++tn)
            #pragma unroll
            for (int r = 0; r < 4; ++r) sc[tn][r] = sa[tn][r] * SCL;
        float vmax[4];
        #pragma unroll
        for (int r = 0; r < 4; ++r) vmax[r] = fmaxf(sc[0][r], sc[1][r]);
        #pragma unroll
        for (int d = 1; d < 16; d <<= 1)
            #pragma unroll
            for (int r = 0; r < 4; ++r) vmax[r] = fmaxf(vmax[r], __shfl_xor(vmax[r], d));
        float p[2][4], rs[4], fac[4];
        #pragma unroll
        for (int r = 0; r < 4; ++r) {
            const float mn = fmaxf(m[r], vmax[r]);
            fac[r] = exp2f(m[r] - mn);
            m[r] = mn;
            p[0][r] = exp2f(sc[0][r] - mn);
            p[1][r] = exp2f(sc[1][r] - mn);
            rs[r] = p[0][r] + p[1][r];
            lsum[r] *= fac[r];
        }
        #pragma unroll
        for (int d = 1; d < 16; d <<= 1)
            #pragma unroll
            for (int r = 0; r < 4; ++r) rs[r] += __shfl_xor(rs[r], d);
        #pragma unroll
        for (int r = 0; r < 4; ++r) lsum[r] += rs[r];
        #pragma unroll
        for (int dt = 0; dt < 8; ++dt)
            #pragma unroll
            for (int r = 0; r < 4; ++r) o[dt][r] *= fac[r];

        #pragma unroll
        for (int r = 0; r < 4; ++r) {
            const int s_ = (l >> 4) * 4 + r;
            Pw[s_ * 40 + (l & 15)]      = (f16)p[0][r];
            Pw[s_ * 40 + 16 + (l & 15)] = (f16)p[1][r];
        }
        asm volatile("s_waitcnt lgkmcnt(0)" ::: "memory");
        f16x8 pa = *(const f16x8*)(Pw + (l & 15) * 40 + (l >> 4) * 8);

        #pragma unroll
        for (int dt = 0; dt < 8; ++dt) o[dt] = MFMA16(pa, vf[dt], o[dt]);
    }

    // ---- merge 8 per-wave partials -> unnormalized block partial ----
    __syncthreads();
    float* Osh = (float*)smem;                 // [8][16][128]
    float* Msh = (float*)(smem + 65536);       // [8][16]
    float* Lsh = Msh + 128;
    #pragma unroll
    for (int dt = 0; dt < 8; ++dt)
        #pragma unroll
        for (int r = 0; r < 4; ++r)
            Osh[w * 2048 + ((l >> 4) * 4 + r) * 128 + dt * 16 + (l & 15)] = o[dt][r];
    if ((l & 15) == 0) {
        #pragma unroll
        for (int r = 0; r < 4; ++r) {
            Msh[w * 16 + (l >> 4) * 4 + r] = m[r];
            Lsh[w * 16 + (l >> 4) * 4 + r] = lsum[r];
        }
    }
    __syncthreads();
    {
        const int s_ = tid >> 5;           // 0..15
        const int d_ = (tid & 31) * 4;     // 0..124
        float M = -3e38f;
        #pragma unroll
        for (int ww = 0; ww < 8; ++ww) M = fmaxf(M, Msh[ww * 16 + s_]);
        float L = 0.f;
        f32x4 oa = {};
        #pragma unroll
        for (int ww = 0; ww < 8; ++ww) {
            const float e = exp2f(Msh[ww * 16 + s_] - M);
            L += e * Lsh[ww * 16 + s_];
            f32x4 v = *(const f32x4*)(Osh + ww * 2048 + s_ * 128 + d_);
            #pragma unroll
            for (int r = 0; r < 4; ++r) oa[r] += e * v[r];
        }
        if ((tid & 31) == 0) {
            Pm[bh * 16 + s_] = M;
            Pl[bh * 16 + s_] = L;
        }
        *(f32x4*)(Po + (size_t)bh * 2048 + s_ * 128 + d_) = oa;
    }
}

// ---------------- kernel F: boundary tokens + final merge ----------------
__global__ __launch_bounds__(256) void k_fin(
        const f16* __restrict__ Qw, const f16* __restrict__ Kw,
        const f16* __restrict__ Vw,
        const float* __restrict__ Kc, const float* __restrict__ Vc,
        const int* __restrict__ posp,
        const float* __restrict__ Pm, const float* __restrict__ Pl,
        const float* __restrict__ Po, f16* __restrict__ Ow) {

    __shared__ float sP[16][48];
    __shared__ float sF[16], sL[16];

    const int bh = blockIdx.x, b = bh >> 5, hh = bh & 31;
    const int tid = threadIdx.x;
    const int pos = *posp;
    const int base = (pos >> 5) << 5;   // first row not covered by pure tiles
    const int nb = pos + 16 - base;     // <= 47

    // ---- phase 1: boundary scores + online-softmax merge stats ----
    {
        const int s_ = tid >> 4, tt0 = tid & 15;
        const f16* qp = Qw + (size_t)(b * 16 + s_) * HID + hh * 128;
        const float m_p = Pm[bh * 16 + s_];
        const float l_p = Pl[bh * 16 + s_];

        float sc[3];
        float rowmax = -3e38f;
        #pragma unroll
        for (int it = 0; it < 3; ++it) {
            const int tt = it * 16 + tt0;
            float d = -3e38f;
            if (tt < nb) {
                const int t = base + tt;
                float acc = 0.f;
                if (t < pos) {
                    const float* kp = Kc + ((size_t)bh * 4096 + t) * 128;
                    #pragma unroll
                    for (int c = 0; c < 16; ++c) {
                        f16x8 q8 = *(const f16x8*)(qp + c * 8);
                        float4 ka = *(const float4*)(kp + c * 8);
                        float4 kb = *(const float4*)(kp + c * 8 + 4);
                        acc += (float)q8[0] * ka.x + (float)q8[1] * ka.y +
                               (float)q8[2] * ka.z + (float)q8[3] * ka.w +
                               (float)q8[4] * kb.x + (float)q8[5] * kb.y +
                               (float)q8[6] * kb.z + (float)q8[7] * kb.w;
                    }
                    d = acc * SCL;
                } else {
                    const f16* kp = Kw + (size_t)(b * 16 + (t - pos)) * HID + hh * 128;
                    #pragma unroll
                    for (int c = 0; c < 16; ++c) {
                        f16x8 q8 = *(const f16x8*)(qp + c * 8);
                        f16x8 k8 = *(const f16x8*)(kp + c * 8);
                        #pragma unroll
                        for (int j = 0; j < 8; ++j) acc += (float)q8[j] * (float)k8[j];
                    }
                    d = acc * SCL;
                    if ((t - pos) > s_) d = -3e38f;   // causal within new tokens
                }
            }
            sc[it] = d;
            rowmax = fmaxf(rowmax, d);
        }
        #pragma unroll
        for (int dd = 1; dd < 16; dd <<= 1)
            rowmax = fmaxf(rowmax, __shfl_xor(rowmax, dd));

        const float M = fmaxf(m_p, rowmax);
        const float fac = exp2f(m_p - M);
        float ps = 0.f;
        #pragma unroll
        for (int it = 0; it < 3; ++it) {
            const float p = (sc[it] < -1e29f) ? 0.f : exp2f(sc[it] - M);
            ps += p;
            sP[s_][it * 16 + tt0] = p;
        }
        #pragma unroll
        for (int dd = 1; dd < 16; dd <<= 1) ps += __shfl_xor(ps, dd);
        if (tt0 == 0) {
            sF[s_] = fac;
            sL[s_] = fac * l_p + ps;
        }
    }
    __syncthreads();

    // ---- phase 2: O = (fac*O_partial + P_b * V_b) / L ----
    {
        const int s2 = tid >> 4;
        const int d0 = (tid & 15) * 8;
        const float f = sF[s2];
        float acc[8];
        const float* po = Po + (size_t)bh * 2048 + s2 * 128 + d0;
        #pragma unroll
        for (int j = 0; j < 8; ++j) acc[j] = f * po[j];

        for (int tt = 0; tt < nb; ++tt) {
            const float pv = sP[s2][tt];
            const int t = base + tt;
            if (t < pos) {
                const float* vp = Vc + ((size_t)bh * 4096 + t) * 128 + d0;
                float4 va = *(const float4*)vp;
                float4 vb = *(const float4*)(vp + 4);
                acc[0] += pv * va.x; acc[1] += pv * va.y;
                acc[2] += pv * va.z; acc[3] += pv * va.w;
                acc[4] += pv * vb.x; acc[5] += pv * vb.y;
                acc[6] += pv * vb.z; acc[7] += pv * vb.w;
            } else {
                const f16* vp = Vw + (size_t)(b * 16 + (t - pos)) * HID + hh * 128 + d0;
                f16x8 v8 = *(const f16x8*)vp;
                #pragma unroll
                for (int j = 0; j < 8; ++j) acc[j] += pv * (float)v8[j];
            }
        }
        const float inv = 1.f / sL[s2];
        f16x8 res;
        #pragma unroll
        for (int j = 0; j < 8; ++j) res[j] = (f16)(acc[j] * inv);
        *(f16x8*)(Ow + (size_t)(b * 16 + s2) * HID + hh * 128 + d0) = res;
    }
}

// ---------------- kernel C: output projection ----------------
__global__ __launch_bounds__(256) void k_oproj(
        const f16* __restrict__ Oa, const float* __restrict__ Wo,
        float* __restrict__ out) {
    const int c0 = blockIdx.x * 16;

    __shared__ __align__(16) f16 sA[128 * 128];
    __shared__ __align__(16) f16 sB[16 * 128];

    const int tid = threadIdx.x;
    const int w = tid >> 6, l = tid & 63;
    const int rw = w * 32;
    const int ar = tid >> 4;
    const int ac = (tid & 15) * 8;

    f32x4 acc0 = {}, acc1 = {};

    float4 wx, wy;
    f16x8 hreg[8];
    {
        const float* wp = Wo + (size_t)(c0 + ar) * HID + ac;
        wx = *(const float4*)wp; wy = *(const float4*)(wp + 4);
        #pragma unroll
        for (int c = 0; c < 8; ++c)
            hreg[c] = *(const f16x8*)(Oa + (size_t)(c * 16 + ar) * HID + ac);
    }

    for (int ks = 0; ks < 32; ++ks) {
        #pragma unroll
        for (int c = 0; c < 8; ++c)
            *(f16x8*)((char*)sA + swz2(c * 16 + ar, ac * 2)) = hreg[c];
        *(f16x8*)((char*)sB + swz2(ar, ac * 2)) = cvt8(wx, wy);
        __syncthreads();
        if (ks < 31) {
            const int k0 = (ks + 1) * 128;
            const float* wp = Wo + (size_t)(c0 + ar) * HID + k0 + ac;
            wx = *(const float4*)wp; wy = *(const float4*)(wp + 4);
            #pragma unroll
            for (int c = 0; c < 8; ++c)
                hreg[c] = *(const f16x8*)(Oa + (size_t)(c * 16 + ar) * HID + k0 + ac);
        }
        #pragma unroll
        for (int kk = 0; kk < 4; ++kk) {
            const int cb = kk * 64 + (l >> 4) * 16;
            f16x8 a0 = *(const f16x8*)((char*)sA + swz2(rw + (l & 15), cb));
            f16x8 a1 = *(const f16x8*)((char*)sA + swz2(rw + 16 + (l & 15), cb));
            f16x8 b0 = *(const f16x8*)((char*)sB + swz2((l & 15), cb));
            acc0 = MFMA16(a0, b0, acc0);
            acc1 = MFMA16(a1, b0, acc1);
        }
        __syncthreads();
    }
    #pragma unroll
    for (int r = 0; r < 4; ++r) {
        const int col = c0 + (l & 15);
        out[(size_t)(rw + (l >> 4) * 4 + r) * HID + col]      = acc0[r];
        out[(size_t)(rw + 16 + (l >> 4) * 4 + r) * HID + col] = acc1[r];
    }
}

extern "C" void kernel_launch(void* const* d_in, const int* in_sizes, int n_in,
                              void* d_out, int out_size, void* d_ws, size_t ws_size,
                              hipStream_t stream) {
    const float* h  = (const float*)d_in[0];
    const float* Wq = (const float*)d_in[1];
    const float* Wk = (const float*)d_in[2];
    const float* Wv = (const float*)d_in[3];
    const float* Wo = (const float*)d_in[4];
    const float* Kc = (const float*)d_in[5];
    const float* Vc = (const float*)d_in[6];
    const int* pos  = (const int*)d_in[7];
    float* out = (float*)d_out;

    f16* hws = (f16*)d_ws;            // 128*4096 f16 = 1 MB
    f16* Qw  = hws + ROWS * HID;
    f16* Kw  = Qw + ROWS * HID;
    f16* Vw  = Kw + ROWS * HID;
    f16* Ow  = Vw + ROWS * HID;
    float* Pm = (float*)(Ow + ROWS * HID);     // 256*16
    float* Pl = Pm + 256 * 16;                 // 256*16
    float* Po = Pl + 256 * 16;                 // 256*2048 f32 = 2 MB

    k_cvt<<<256, 256, 0, stream>>>(h, hws);
    k_qproj<<<256, 256, 0, stream>>>(hws, Wq, Qw);
    k_mega<<<512, 512, 0, stream>>>(hws, Wk, Wv, Kw, Vw, Qw, Kc, Vc, pos, Pm, Pl, Po);
    k_fin<<<256, 256, 0, stream>>>(Qw, Kw, Vw, Kc, Vc, pos, Pm, Pl, Po, Ow);
    k_oproj<<<256, 256, 0, stream>>>(Ow, Wo, out);
}

// Round 4
// 218.669 us; speedup vs baseline: 1.0475x; 1.0475x over previous
//
#include <hip/hip_runtime.h>

typedef _Float16 f16;
typedef _Float16 f16x8 __attribute__((ext_vector_type(8)));
typedef _Float16 f16x4 __attribute__((ext_vector_type(4)));
typedef _Float16 f16x2 __attribute__((ext_vector_type(2)));
typedef float f32x4 __attribute__((ext_vector_type(4)));
typedef float f32x2 __attribute__((ext_vector_type(2)));

#define MFMA16(a, b, c) __builtin_amdgcn_mfma_f32_16x16x32_f16(a, b, c, 0, 0, 0)

#define HID 4096
#define ROWS 128      // B*S
#define SCL 0.12751743f  // (1/sqrt(128)) * log2(e)

__device__ __forceinline__ f16x8 cvt8(float4 x, float4 y) {
    f16x8 v = {(f16)x.x, (f16)x.y, (f16)x.z, (f16)x.w,
               (f16)y.x, (f16)y.y, (f16)y.z, (f16)y.w};
    return v;
}

// XOR swizzle for a tile with 128 f16 (256 B) row pitch
__device__ __forceinline__ int swz2(int row, int cb) {
    return row * 256 + (cb ^ ((row & 7) << 4));
}

// ---------------- kernel 0: h fp32 -> f16 ----------------
__global__ void k_cvt(const float* __restrict__ src, f16* __restrict__ dst) {
    const int i = blockIdx.x * blockDim.x + threadIdx.x;
    const float4* s4 = (const float4*)src + (size_t)i * 2;
    float4 x = s4[0], y = s4[1];
    *((f16x8*)dst + i) = cvt8(x, y);
}

// ---------------- kernel A: fused QKV projection (as R2) ----------------
__global__ __launch_bounds__(256) void k_proj(
        const f16* __restrict__ hb,
        const float* __restrict__ Wq, const float* __restrict__ Wk,
        const float* __restrict__ Wv,
        f16* __restrict__ Qw, f16* __restrict__ Kw, f16* __restrict__ Vw) {
    const int mat = blockIdx.x >> 8;
    const int ct  = blockIdx.x & 255;
    const float* __restrict__ W = (mat == 0) ? Wq : (mat == 1) ? Wk : Wv;
    f16* __restrict__ Ob = (mat == 0) ? Qw : (mat == 1) ? Kw : Vw;
    const int c0 = ct * 16;

    __shared__ __align__(16) f16 sA[128 * 128];
    __shared__ __align__(16) f16 sB[16 * 128];

    const int tid = threadIdx.x;
    const int w = tid >> 6, l = tid & 63;
    const int rw = w * 32;
    const int ar = tid >> 4;
    const int ac = (tid & 15) * 8;

    f32x4 acc0 = {}, acc1 = {};

    float4 wx, wy;
    f16x8 hreg[8];
    {
        const float* wp = W + (size_t)(c0 + ar) * HID + ac;
        wx = *(const float4*)wp; wy = *(const float4*)(wp + 4);
        #pragma unroll
        for (int c = 0; c < 8; ++c)
            hreg[c] = *(const f16x8*)(hb + (size_t)(c * 16 + ar) * HID + ac);
    }

    for (int ks = 0; ks < 32; ++ks) {
        #pragma unroll
        for (int c = 0; c < 8; ++c)
            *(f16x8*)((char*)sA + swz2(c * 16 + ar, ac * 2)) = hreg[c];
        *(f16x8*)((char*)sB + swz2(ar, ac * 2)) = cvt8(wx, wy);
        __syncthreads();
        if (ks < 31) {
            const int k0 = (ks + 1) * 128;
            const float* wp = W + (size_t)(c0 + ar) * HID + k0 + ac;
            wx = *(const float4*)wp; wy = *(const float4*)(wp + 4);
            #pragma unroll
            for (int c = 0; c < 8; ++c)
                hreg[c] = *(const f16x8*)(hb + (size_t)(c * 16 + ar) * HID + k0 + ac);
        }
        #pragma unroll
        for (int kk = 0; kk < 4; ++kk) {
            const int cb = kk * 64 + (l >> 4) * 16;
            f16x8 a0 = *(const f16x8*)((char*)sA + swz2(rw + (l & 15), cb));
            f16x8 a1 = *(const f16x8*)((char*)sA + swz2(rw + 16 + (l & 15), cb));
            f16x8 b0 = *(const f16x8*)((char*)sB + swz2((l & 15), cb));
            acc0 = MFMA16(a0, b0, acc0);
            acc1 = MFMA16(a1, b0, acc1);
        }
        __syncthreads();
    }
    #pragma unroll
    for (int r = 0; r < 4; ++r) {
        const int col = c0 + (l & 15);
        Ob[(size_t)(rw + (l >> 4) * 4 + r) * HID + col]      = (f16)acc0[r];
        Ob[(size_t)(rw + 16 + (l >> 4) * 4 + r) * HID + col] = (f16)acc1[r];
    }
}

// ---------------- kernel B: flash attention, 2 blocks per (b,h), 8 waves ----------------
// Each block covers half the pure KV tiles; writes unnormalized partial (m,l,O).
__global__ __launch_bounds__(512) void k_attn(
        const f16* __restrict__ Qw,
        const float* __restrict__ Kc, const float* __restrict__ Vc,
        const int* __restrict__ posp,
        float* __restrict__ Pm, float* __restrict__ Pl, float* __restrict__ Po) {

    __shared__ __align__(16) char smem[65536 + 1024];

    const int bh = blockIdx.x >> 1;
    const int q  = blockIdx.x & 1;
    const int b = bh >> 5, hh = bh & 31;
    const int tid = threadIdx.x, w = tid >> 6, l = tid & 63;
    const int pos = *posp;
    const int npure = pos >> 5;
    const int nblk = npure >> 1;          // tiles per block
    const int tbase = q * nblk;

    const float* Kb = Kc + (size_t)bh * (4096 * 128);
    const float* Vb = Vc + (size_t)bh * (4096 * 128);

    f16x8 qf[4];
    {
        const f16* qp = Qw + (size_t)(b * 16 + (l & 15)) * HID + hh * 128 + (l >> 4) * 8;
        #pragma unroll
        for (int kk = 0; kk < 4; ++kk) qf[kk] = *(const f16x8*)(qp + kk * 32);
    }

    f32x4 o[8] = {};
    float m[4], lsum[4];
    #pragma unroll
    for (int r = 0; r < 4; ++r) { m[r] = -3e38f; lsum[r] = 0.f; }

    f16* Pw = (f16*)smem + w * 640;

    const int start = tbase + ((w * nblk) >> 3);
    const int end   = tbase + (((w + 1) * nblk) >> 3);
    for (int tau = start; tau < end; ++tau) {
        const int t0 = tau << 5;

        f16x8 kf[2][4];
        #pragma unroll
        for (int tn = 0; tn < 2; ++tn) {
            const float* kp = Kb + (size_t)(t0 + tn * 16 + (l & 15)) * 128 + (l >> 4) * 8;
            #pragma unroll
            for (int kk = 0; kk < 4; ++kk) {
                float4 x = *(const float4*)(kp + kk * 32);
                float4 y = *(const float4*)(kp + kk * 32 + 4);
                kf[tn][kk] = cvt8(x, y);
            }
        }
        f32x4 sa[2] = {};
        #pragma unroll
        for (int tn = 0; tn < 2; ++tn)
            #pragma unroll
            for (int kk = 0; kk < 4; ++kk) sa[tn] = MFMA16(qf[kk], kf[tn][kk], sa[tn]);

        // V gather issued now; latency hides under softmax + P transpose
        f16x8 vf[8];
        {
            const float* vp = Vb + (size_t)(t0 + (l >> 4) * 8) * 128 + (l & 15);
            #pragma unroll
            for (int dt = 0; dt < 8; ++dt)
                #pragma unroll
                for (int j = 0; j < 8; ++j) vf[dt][j] = (f16)vp[j * 128 + dt * 16];
        }

        float sc[2][4];
        #pragma unroll
        for (int tn = 0; tn < 2; ++tn)
            #pragma unroll
            for (int r = 0; r < 4; ++r) sc[tn][r] = sa[tn][r] * SCL;
        float vmax[4];
        #pragma unroll
        for (int r = 0; r < 4; ++r) vmax[r] = fmaxf(sc[0][r], sc[1][r]);
        #pragma unroll
        for (int d = 1; d < 16; d <<= 1)
            #pragma unroll
            for (int r = 0; r < 4; ++r) vmax[r] = fmaxf(vmax[r], __shfl_xor(vmax[r], d));
        float p[2][4], rs[4], fac[4];
        #pragma unroll
        for (int r = 0; r < 4; ++r) {
            const float mn = fmaxf(m[r], vmax[r]);
            fac[r] = exp2f(m[r] - mn);
            m[r] = mn;
            p[0][r] = exp2f(sc[0][r] - mn);
            p[1][r] = exp2f(sc[1][r] - mn);
            rs[r] = p[0][r] + p[1][r];
            lsum[r] *= fac[r];
        }
        #pragma unroll
        for (int d = 1; d < 16; d <<= 1)
            #pragma unroll
            for (int r = 0; r < 4; ++r) rs[r] += __shfl_xor(rs[r], d);
        #pragma unroll
        for (int r = 0; r < 4; ++r) lsum[r] += rs[r];
        #pragma unroll
        for (int dt = 0; dt < 8; ++dt)
            #pragma unroll
            for (int r = 0; r < 4; ++r) o[dt][r] *= fac[r];

        #pragma unroll
        for (int r = 0; r < 4; ++r) {
            const int s_ = (l >> 4) * 4 + r;
            Pw[s_ * 40 + (l & 15)]      = (f16)p[0][r];
            Pw[s_ * 40 + 16 + (l & 15)] = (f16)p[1][r];
        }
        asm volatile("s_waitcnt lgkmcnt(0)" ::: "memory");
        f16x8 pa = *(const f16x8*)(Pw + (l & 15) * 40 + (l >> 4) * 8);

        #pragma unroll
        for (int dt = 0; dt < 8; ++dt) o[dt] = MFMA16(pa, vf[dt], o[dt]);
    }

    // ---- merge 8 per-wave partials -> unnormalized block partial ----
    __syncthreads();
    float* Osh = (float*)smem;                 // [8][16][128]
    float* Msh = (float*)(smem + 65536);       // [8][16]
    float* Lsh = Msh + 128;
    #pragma unroll
    for (int dt = 0; dt < 8; ++dt)
        #pragma unroll
        for (int r = 0; r < 4; ++r)
            Osh[w * 2048 + ((l >> 4) * 4 + r) * 128 + dt * 16 + (l & 15)] = o[dt][r];
    if ((l & 15) == 0) {
        #pragma unroll
        for (int r = 0; r < 4; ++r) {
            Msh[w * 16 + (l >> 4) * 4 + r] = m[r];
            Lsh[w * 16 + (l >> 4) * 4 + r] = lsum[r];
        }
    }
    __syncthreads();
    {
        const int pb = blockIdx.x;         // partial index
        const int s_ = tid >> 5;           // 0..15
        const int d_ = (tid & 31) * 4;     // 0..124
        float M = -3e38f;
        #pragma unroll
        for (int ww = 0; ww < 8; ++ww) M = fmaxf(M, Msh[ww * 16 + s_]);
        float L = 0.f;
        f32x4 oa = {};
        #pragma unroll
        for (int ww = 0; ww < 8; ++ww) {
            const float e = exp2f(Msh[ww * 16 + s_] - M);
            L += e * Lsh[ww * 16 + s_];
            f32x4 v = *(const f32x4*)(Osh + ww * 2048 + s_ * 128 + d_);
            #pragma unroll
            for (int r = 0; r < 4; ++r) oa[r] += e * v[r];
        }
        if ((tid & 31) == 0) {
            Pm[pb * 16 + s_] = M;
            Pl[pb * 16 + s_] = L;
        }
        *(f32x4*)(Po + (size_t)pb * 2048 + s_ * 128 + d_) = oa;
    }
}

// ---------------- kernel F: boundary tokens + final merge of 2 partials ----------------
__global__ __launch_bounds__(256) void k_fin(
        const f16* __restrict__ Qw, const f16* __restrict__ Kw,
        const f16* __restrict__ Vw,
        const float* __restrict__ Kc, const float* __restrict__ Vc,
        const int* __restrict__ posp,
        const float* __restrict__ Pm, const float* __restrict__ Pl,
        const float* __restrict__ Po, f16* __restrict__ Ow) {

    __shared__ float sP[16][48];
    __shared__ float sF0[16], sF1[16], sL[16];

    const int bh = blockIdx.x, b = bh >> 5, hh = bh & 31;
    const int tid = threadIdx.x;
    const int pos = *posp;
    const int base = (pos >> 5) << 5;   // first row not covered by pure tiles
    const int nb = pos + 16 - base;     // <= 47

    // ---- phase 1: boundary scores + online-softmax merge stats ----
    {
        const int s_ = tid >> 4, tt0 = tid & 15;
        const f16* qp = Qw + (size_t)(b * 16 + s_) * HID + hh * 128;
        const float m0 = Pm[(bh * 2) * 16 + s_];
        const float m1 = Pm[(bh * 2 + 1) * 16 + s_];
        const float l0 = Pl[(bh * 2) * 16 + s_];
        const float l1 = Pl[(bh * 2 + 1) * 16 + s_];

        float sc[3];
        float rowmax = -3e38f;
        #pragma unroll
        for (int it = 0; it < 3; ++it) {
            const int tt = it * 16 + tt0;
            float d = -3e38f;
            if (tt < nb) {
                const int t = base + tt;
                float acc = 0.f;
                if (t < pos) {
                    const float* kp = Kc + ((size_t)bh * 4096 + t) * 128;
                    #pragma unroll
                    for (int c = 0; c < 16; ++c) {
                        f16x8 q8 = *(const f16x8*)(qp + c * 8);
                        float4 ka = *(const float4*)(kp + c * 8);
                        float4 kb = *(const float4*)(kp + c * 8 + 4);
                        acc += (float)q8[0] * ka.x + (float)q8[1] * ka.y +
                               (float)q8[2] * ka.z + (float)q8[3] * ka.w +
                               (float)q8[4] * kb.x + (float)q8[5] * kb.y +
                               (float)q8[6] * kb.z + (float)q8[7] * kb.w;
                    }
                    d = acc * SCL;
                } else {
                    const f16* kp = Kw + (size_t)(b * 16 + (t - pos)) * HID + hh * 128;
                    #pragma unroll
                    for (int c = 0; c < 16; ++c) {
                        f16x8 q8 = *(const f16x8*)(qp + c * 8);
                        f16x8 k8 = *(const f16x8*)(kp + c * 8);
                        #pragma unroll
                        for (int j = 0; j < 8; ++j) acc += (float)q8[j] * (float)k8[j];
                    }
                    d = acc * SCL;
                    if ((t - pos) > s_) d = -3e38f;   // causal within new tokens
                }
            }
            sc[it] = d;
            rowmax = fmaxf(rowmax, d);
        }
        #pragma unroll
        for (int dd = 1; dd < 16; dd <<= 1)
            rowmax = fmaxf(rowmax, __shfl_xor(rowmax, dd));

        const float M = fmaxf(fmaxf(m0, m1), rowmax);
        const float f0 = exp2f(m0 - M);
        const float f1 = exp2f(m1 - M);
        float ps = 0.f;
        #pragma unroll
        for (int it = 0; it < 3; ++it) {
            const float p = (sc[it] < -1e29f) ? 0.f : exp2f(sc[it] - M);
            ps += p;
            sP[s_][it * 16 + tt0] = p;
        }
        #pragma unroll
        for (int dd = 1; dd < 16; dd <<= 1) ps += __shfl_xor(ps, dd);
        if (tt0 == 0) {
            sF0[s_] = f0;
            sF1[s_] = f1;
            sL[s_] = f0 * l0 + f1 * l1 + ps;
        }
    }
    __syncthreads();

    // ---- phase 2: O = (f0*O0 + f1*O1 + P_b * V_b) / L ----
    {
        const int s2 = tid >> 4;
        const int d0 = (tid & 15) * 8;
        const float f0 = sF0[s2], f1 = sF1[s2];
        float acc[8];
        const float* po0 = Po + (size_t)(bh * 2) * 2048 + s2 * 128 + d0;
        const float* po1 = Po + (size_t)(bh * 2 + 1) * 2048 + s2 * 128 + d0;
        #pragma unroll
        for (int j = 0; j < 8; ++j) acc[j] = f0 * po0[j] + f1 * po1[j];

        for (int tt = 0; tt < nb; ++tt) {
            const float pv = sP[s2][tt];
            const int t = base + tt;
            if (t < pos) {
                const float* vp = Vc + ((size_t)bh * 4096 + t) * 128 + d0;
                float4 va = *(const float4*)vp;
                float4 vb = *(const float4*)(vp + 4);
                acc[0] += pv * va.x; acc[1] += pv * va.y;
                acc[2] += pv * va.z; acc[3] += pv * va.w;
                acc[4] += pv * vb.x; acc[5] += pv * vb.y;
                acc[6] += pv * vb.z; acc[7] += pv * vb.w;
            } else {
                const f16* vp = Vw + (size_t)(b * 16 + (t - pos)) * HID + hh * 128 + d0;
                f16x8 v8 = *(const f16x8*)vp;
                #pragma unroll
                for (int j = 0; j < 8; ++j) acc[j] += pv * (float)v8[j];
            }
        }
        const float inv = 1.f / sL[s2];
        f16x8 res;
        #pragma unroll
        for (int j = 0; j < 8; ++j) res[j] = (f16)(acc[j] * inv);
        *(f16x8*)(Ow + (size_t)(b * 16 + s2) * HID + hh * 128 + d0) = res;
    }
}

// ---------------- kernel C: output projection (as R2) ----------------
__global__ __launch_bounds__(256) void k_oproj(
        const f16* __restrict__ Oa, const float* __restrict__ Wo,
        float* __restrict__ out) {
    const int c0 = blockIdx.x * 16;

    __shared__ __align__(16) f16 sA[128 * 128];
    __shared__ __align__(16) f16 sB[16 * 128];

    const int tid = threadIdx.x;
    const int w = tid >> 6, l = tid & 63;
    const int rw = w * 32;
    const int ar = tid >> 4;
    const int ac = (tid & 15) * 8;

    f32x4 acc0 = {}, acc1 = {};

    float4 wx, wy;
    f16x8 hreg[8];
    {
        const float* wp = Wo + (size_t)(c0 + ar) * HID + ac;
        wx = *(const float4*)wp; wy = *(const float4*)(wp + 4);
        #pragma unroll
        for (int c = 0; c < 8; ++c)
            hreg[c] = *(const f16x8*)(Oa + (size_t)(c * 16 + ar) * HID + ac);
    }

    for (int ks = 0; ks < 32; ++ks) {
        #pragma unroll
        for (int c = 0; c < 8; ++c)
            *(f16x8*)((char*)sA + swz2(c * 16 + ar, ac * 2)) = hreg[c];
        *(f16x8*)((char*)sB + swz2(ar, ac * 2)) = cvt8(wx, wy);
        __syncthreads();
        if (ks < 31) {
            const int k0 = (ks + 1) * 128;
            const float* wp = Wo + (size_t)(c0 + ar) * HID + k0 + ac;
            wx = *(const float4*)wp; wy = *(const float4*)(wp + 4);
            #pragma unroll
            for (int c = 0; c < 8; ++c)
                hreg[c] = *(const f16x8*)(Oa + (size_t)(c * 16 + ar) * HID + k0 + ac);
        }
        #pragma unroll
        for (int kk = 0; kk < 4; ++kk) {
            const int cb = kk * 64 + (l >> 4) * 16;
            f16x8 a0 = *(const f16x8*)((char*)sA + swz2(rw + (l & 15), cb));
            f16x8 a1 = *(const f16x8*)((char*)sA + swz2(rw + 16 + (l & 15), cb));
            f16x8 b0 = *(const f16x8*)((char*)sB + swz2((l & 15), cb));
            acc0 = MFMA16(a0, b0, acc0);
            acc1 = MFMA16(a1, b0, acc1);
        }
        __syncthreads();
    }
    #pragma unroll
    for (int r = 0; r < 4; ++r) {
        const int col = c0 + (l & 15);
        out[(size_t)(rw + (l >> 4) * 4 + r) * HID + col]      = acc0[r];
        out[(size_t)(rw + 16 + (l >> 4) * 4 + r) * HID + col] = acc1[r];
    }
}

extern "C" void kernel_launch(void* const* d_in, const int* in_sizes, int n_in,
                              void* d_out, int out_size, void* d_ws, size_t ws_size,
                              hipStream_t stream) {
    const float* h  = (const float*)d_in[0];
    const float* Wq = (const float*)d_in[1];
    const float* Wk = (const float*)d_in[2];
    const float* Wv = (const float*)d_in[3];
    const float* Wo = (const float*)d_in[4];
    const float* Kc = (const float*)d_in[5];
    const float* Vc = (const float*)d_in[6];
    const int* pos  = (const int*)d_in[7];
    float* out = (float*)d_out;

    f16* hws = (f16*)d_ws;            // 128*4096 f16 = 1 MB
    f16* Qw  = hws + ROWS * HID;
    f16* Kw  = Qw + ROWS * HID;
    f16* Vw  = Kw + ROWS * HID;
    f16* Ow  = Vw + ROWS * HID;
    float* Pm = (float*)(Ow + ROWS * HID);     // 512*16
    float* Pl = Pm + 512 * 16;                 // 512*16
    float* Po = Pl + 512 * 16;                 // 512*2048 f32 = 4 MB

    k_cvt<<<256, 256, 0, stream>>>(h, hws);
    k_proj<<<768, 256, 0, stream>>>(hws, Wq, Wk, Wv, Qw, Kw, Vw);
    k_attn<<<512, 512, 0, stream>>>(Qw, Kc, Vc, pos, Pm, Pl, Po);
    k_fin<<<256, 256, 0, stream>>>(Qw, Kw, Vw, Kc, Vc, pos, Pm, Pl, Po, Ow);
    k_oproj<<<256, 256, 0, stream>>>(Ow, Wo, out);
}